// Round 4
// baseline (11666.274 us; speedup 1.0000x reference)
//
#include <hip/hip_runtime.h>

#define NB 8
#define NQ 2048
#define NK 2048
#define ND 512
#define MASK_VALUE (-1e-06f)

typedef __attribute__((ext_vector_type(4))) float f32x4;
typedef f32x4 __attribute__((may_alias)) f32x4_ma;

// ---------- stage 1: QW[row][e] = sum_d Q[row][d] * W[d][e]; one thread -> 4 e ----------
__global__ __launch_bounds__(256)
void qw_kernel(const float* __restrict__ Q, const float* __restrict__ W,
               float* __restrict__ QW)
{
    const size_t gid = (size_t)blockIdx.x * 256 + threadIdx.x;   // NB*NQ*(ND/4) total
    const int    e4  = ((int)(gid & (ND/4 - 1))) * 4;            // ND/4 = 128
    const size_t row = gid >> 7;                                 // b*NQ + q
    const float* qrow = Q + row * ND;
    float a0=0,a1=0,a2=0,a3=0, b0=0,b1=0,b2=0,b3=0;
    for (int d = 0; d < ND; d += 2){
        const float q0 = qrow[d];
        const float q1 = qrow[d+1];
        const f32x4 w0 = *(const f32x4_ma*)&W[(size_t)d*ND + e4];
        const f32x4 w1 = *(const f32x4_ma*)&W[(size_t)(d+1)*ND + e4];
        a0 += q0*w0[0]; a1 += q0*w0[1]; a2 += q0*w0[2]; a3 += q0*w0[3];
        b0 += q1*w1[0]; b1 += q1*w1[1]; b2 += q1*w1[2]; b3 += q1*w1[3];
    }
    f32x4 r; r[0]=a0+b0; r[1]=a1+b1; r[2]=a2+b2; r[3]=a3+b3;
    *(f32x4_ma*)&QW[row*ND + e4] = r;
}

// ---------- stage 2: attention, naive fp32, flash-tiled over 64 keys ----------
__global__ __launch_bounds__(256)
void attn_kernel(const float* __restrict__ QW, const float* __restrict__ K,
                 const float* __restrict__ V, const int* __restrict__ Mp,
                 float* __restrict__ O)
{
    __shared__ float qw_s[16][516];   // +4 pad: lanes read different rows, same col
    __shared__ float s_s[16][68];
    __shared__ float p_s[16][68];
    __shared__ float m_s[16], f_s[16], l_s[16];

    const int tid = threadIdx.x;
    const int b   = blockIdx.x & 7;               // batch -> XCD affinity
    const int q0  = (int)(blockIdx.x >> 3) * 16;

    int mk;
    {   // tolerate int64-encoded masks: genuine int32 masks are >=1, so the
        // odd int32 words can only all be zero if data is (value,0) int64 pairs
        const int odd = Mp[1] | Mp[3] | Mp[5] | Mp[7];
        mk = (odd == 0) ? Mp[2*b] : Mp[b];
    }

    // stage qw tile [16][512]
    {
        const int r  = tid >> 4;
        const int c0 = (tid & 15) * 32;
        #pragma unroll
        for (int j = 0; j < 8; ++j)
            *(f32x4_ma*)&qw_s[r][c0 + 4*j] =
                *(const f32x4_ma*)&QW[((size_t)b*NQ + q0 + r)*ND + c0 + 4*j];
    }
    if (tid < 16){ m_s[tid] = -3.0e38f; l_s[tid] = 0.f; }

    // PV ownership: row rp, d-columns dp..dp+31 (all indices static-unrolled)
    const int rp = tid >> 4;
    const int dp = (tid & 15) * 32;
    float o[32];
    #pragma unroll
    for (int j = 0; j < 32; ++j) o[j] = 0.f;

    // score ownership: row rs, tile-cols cs..cs+3
    const int rs = tid & 15;
    const int cs = (tid >> 4) * 4;

    __syncthreads();

    for (int k0 = 0; k0 < NK; k0 += 64){
        // ---- scores: S[rs][cs..cs+3] ----
        #pragma unroll
        for (int cc = 0; cc < 4; ++cc){
            const int kk = k0 + cs + cc;
            const float* krow = K + ((size_t)b*NK + kk)*ND;
            f32x4 acc = {0.f, 0.f, 0.f, 0.f};
            for (int e = 0; e < ND; e += 4){
                const f32x4 kv = *(const f32x4_ma*)&krow[e];
                const f32x4 qv = *(const f32x4_ma*)&qw_s[rs][e];
                acc[0] += qv[0]*kv[0]; acc[1] += qv[1]*kv[1];
                acc[2] += qv[2]*kv[2]; acc[3] += qv[3]*kv[3];
            }
            const float dot = (acc[0]+acc[1]) + (acc[2]+acc[3]);
            // faithful mask: replaced by tiny negative, STAYS in softmax
            s_s[rs][cs + cc] = (kk < mk) ? dot : MASK_VALUE;
        }
        __syncthreads();

        // ---- row max + rescale factor (serial leaders: transparent) ----
        if (tid < 16){
            float tmax = s_s[tid][0];
            for (int c = 1; c < 64; ++c) tmax = fmaxf(tmax, s_s[tid][c]);
            const float mnew = fmaxf(m_s[tid], tmax);
            f_s[tid] = __expf(m_s[tid] - mnew);   // first tile: exp(-3e38) = 0
            m_s[tid] = mnew;
        }
        __syncthreads();

        // ---- p = exp(s - m) ----
        #pragma unroll
        for (int cc = 0; cc < 4; ++cc)
            p_s[rs][cs+cc] = __expf(s_s[rs][cs+cc] - m_s[rs]);
        __syncthreads();

        // ---- denominator update (leaders) + PV (all threads), both read-only on p_s ----
        if (tid < 16){
            float ps = 0.f;
            for (int c = 0; c < 64; ++c) ps += p_s[tid][c];
            l_s[tid] = l_s[tid]*f_s[tid] + ps;
        }
        {
            const float fr = f_s[rp];
            #pragma unroll
            for (int j = 0; j < 32; ++j) o[j] *= fr;
            for (int c = 0; c < 64; ++c){
                const float p = p_s[rp][c];
                const float* vrow = V + ((size_t)b*NK + k0 + c)*ND + dp;
                #pragma unroll
                for (int j8 = 0; j8 < 8; ++j8){
                    const f32x4 vv = *(const f32x4_ma*)&vrow[4*j8];
                    o[4*j8+0] += p*vv[0]; o[4*j8+1] += p*vv[1];
                    o[4*j8+2] += p*vv[2]; o[4*j8+3] += p*vv[3];
                }
            }
        }
        __syncthreads();
    }

    // ---- epilogue: normalize by the SAME p-sum used in PV ----
    {
        const float li = 1.f / l_s[rp];
        #pragma unroll
        for (int j8 = 0; j8 < 8; ++j8){
            f32x4 r;
            r[0] = o[4*j8+0]*li; r[1] = o[4*j8+1]*li;
            r[2] = o[4*j8+2]*li; r[3] = o[4*j8+3]*li;
            *(f32x4_ma*)&O[((size_t)b*NQ + q0 + rp)*ND + dp + 4*j8] = r;
        }
    }
}

extern "C" void kernel_launch(void* const* d_in, const int* in_sizes, int n_in,
                              void* d_out, int out_size, void* d_ws, size_t ws_size,
                              hipStream_t stream)
{
    (void)in_sizes; (void)n_in; (void)out_size; (void)ws_size;
    const float* Qp = (const float*)d_in[0];
    const float* Kp = (const float*)d_in[1];
    const float* Vp = (const float*)d_in[2];
    const float* Wp = (const float*)d_in[3];
    const int*   Mp = (const int*)  d_in[4];
    float* Op = (float*)d_out;

    float* QW = (float*)d_ws;   // 8*2048*512*4 = 33.5 MB scratch

    hipLaunchKernelGGL(qw_kernel, dim3(NB*NQ*(ND/4)/256), dim3(256), 0, stream,
                       Qp, Wp, QW);
    hipLaunchKernelGGL(attn_kernel, dim3(NB*(NQ/16)), dim3(256), 0, stream,
                       QW, Kp, Vp, Mp, Op);
}

// Round 5
// 7901.877 us; speedup vs baseline: 1.4764x; 1.4764x over previous
//
#include <hip/hip_runtime.h>

#define NB 8
#define NQ 2048
#define NK 2048
#define ND 512
#define MASK_VALUE (-1e-06f)

typedef __attribute__((ext_vector_type(4))) float f32x4;
typedef __attribute__((ext_vector_type(8))) __bf16 bf16x8;
typedef __attribute__((ext_vector_type(4))) unsigned int u32x4;
typedef __attribute__((ext_vector_type(2))) unsigned int u32x2;

typedef f32x4  __attribute__((may_alias)) f32x4_ma;
typedef bf16x8 __attribute__((may_alias)) bf16x8_ma;
typedef u32x4  __attribute__((may_alias)) u32x4_ma;
typedef u32x2  __attribute__((may_alias)) u32x2_ma;

__device__ __forceinline__ unsigned short f2bf(float x){
    union { float f; unsigned u; } v; v.f = x;
    unsigned r = v.u + 0x7fffu + ((v.u >> 16) & 1u);
    return (unsigned short)(r >> 16);
}
__device__ __forceinline__ float bf2f(unsigned short h){
    union { unsigned u; float f; } v; v.u = ((unsigned)h) << 16;
    return v.f;
}

// ---------- stage 1 (UNCHANGED from passing probe): QW = Q @ W, fp32 ----------
__global__ __launch_bounds__(256)
void qw_kernel(const float* __restrict__ Q, const float* __restrict__ W,
               float* __restrict__ QW)
{
    const size_t gid = (size_t)blockIdx.x * 256 + threadIdx.x;
    const int    e4  = ((int)(gid & (ND/4 - 1))) * 4;
    const size_t row = gid >> 7;
    const float* qrow = Q + row * ND;
    float a0=0,a1=0,a2=0,a3=0, b0=0,b1=0,b2=0,b3=0;
    for (int d = 0; d < ND; d += 2){
        const float q0 = qrow[d];
        const float q1 = qrow[d+1];
        const f32x4 w0 = *(const f32x4_ma*)&W[(size_t)d*ND + e4];
        const f32x4 w1 = *(const f32x4_ma*)&W[(size_t)(d+1)*ND + e4];
        a0 += q0*w0[0]; a1 += q0*w0[1]; a2 += q0*w0[2]; a3 += q0*w0[3];
        b0 += q1*w1[0]; b1 += q1*w1[1]; b2 += q1*w1[2]; b3 += q1*w1[3];
    }
    f32x4 r; r[0]=a0+b0; r[1]=a1+b1; r[2]=a2+b2; r[3]=a3+b3;
    *(f32x4_ma*)&QW[row*ND + e4] = r;
}

// ---------- stage 2: QK via MFMA (hi/lo bf16), softmax+PV fp32 (verbatim probe) ----------
__global__ __launch_bounds__(256)
void attn_kernel(const float* __restrict__ QW, const float* __restrict__ K,
                 const float* __restrict__ V, const int* __restrict__ Mp,
                 float* __restrict__ O)
{
    __shared__ unsigned short qw_h[16][520];
    __shared__ unsigned short qw_l[16][520];
    __shared__ unsigned short kbh[64][72];
    __shared__ unsigned short kbl[64][72];
    __shared__ float s_s[16][68];
    __shared__ float p_s[16][68];
    __shared__ float m_s[16], f_s[16], l_s[16];

    const int tid  = threadIdx.x;
    const int lane = tid & 63;
    const int wv   = tid >> 6;
    const int lm   = lane & 15;
    const int lg   = lane >> 4;
    const int b    = blockIdx.x & 7;               // batch -> XCD affinity
    const int q0   = (int)(blockIdx.x >> 3) * 16;

    int mk;
    {   // tolerate int64-encoded masks (values >=1, so odd words all-zero => int64)
        const int odd = Mp[1] | Mp[3] | Mp[5] | Mp[7];
        mk = (odd == 0) ? Mp[2*b] : Mp[b];
    }

    // stage qw tile [16][512] -> hi/lo bf16 planes
    {
        const int r  = tid >> 4;
        const int c0 = (tid & 15) * 32;
        #pragma unroll
        for (int j = 0; j < 8; ++j){
            const f32x4 qv = *(const f32x4_ma*)&QW[((size_t)b*NQ + q0 + r)*ND + c0 + 4*j];
            unsigned short h[4], l[4];
            #pragma unroll
            for (int c = 0; c < 4; ++c){
                h[c] = f2bf(qv[c]);
                l[c] = f2bf(qv[c] - bf2f(h[c]));
            }
            u32x2 hv, lv;
            hv[0] = (unsigned)h[0] | ((unsigned)h[1] << 16);
            hv[1] = (unsigned)h[2] | ((unsigned)h[3] << 16);
            lv[0] = (unsigned)l[0] | ((unsigned)l[1] << 16);
            lv[1] = (unsigned)l[2] | ((unsigned)l[3] << 16);
            *(u32x2_ma*)&qw_h[r][c0 + 4*j] = hv;
            *(u32x2_ma*)&qw_l[r][c0 + 4*j] = lv;
        }
    }
    if (tid < 16){ m_s[tid] = -3.0e38f; l_s[tid] = 0.f; }

    // PV ownership (probe-verbatim)
    const int rp = tid >> 4;
    const int dp = (tid & 15) * 32;
    float o[32];
    #pragma unroll
    for (int j = 0; j < 32; ++j) o[j] = 0.f;

    // p_s ownership (probe-verbatim)
    const int rs = tid & 15;
    const int cs = (tid >> 4) * 4;

    __syncthreads();

    for (int k0 = 0; k0 < NK; k0 += 64){
        // ---- QK^T via MFMA: wave wv owns key-cols [wv*16, wv*16+16) of the tile ----
        f32x4 sacc = {0.f, 0.f, 0.f, 0.f};
        for (int ec = 0; ec < 8; ++ec){
            __syncthreads();                 // kb planes free of previous readers
            {   // stage K chunk [64 keys][64 e] -> hi/lo bf16
                const int c4 = (tid & 15) * 4;
                #pragma unroll
                for (int m4 = 0; m4 < 4; ++m4){
                    const int kr = (tid >> 4) + m4*16;
                    const f32x4 kv = *(const f32x4_ma*)&K[((size_t)b*NK + k0 + kr)*ND + ec*64 + c4];
                    unsigned short h[4], l[4];
                    #pragma unroll
                    for (int c = 0; c < 4; ++c){
                        h[c] = f2bf(kv[c]);
                        l[c] = f2bf(kv[c] - bf2f(h[c]));
                    }
                    u32x2 hv, lv;
                    hv[0] = (unsigned)h[0] | ((unsigned)h[1] << 16);
                    hv[1] = (unsigned)h[2] | ((unsigned)h[3] << 16);
                    lv[0] = (unsigned)l[0] | ((unsigned)l[1] << 16);
                    lv[1] = (unsigned)l[2] | ((unsigned)l[3] << 16);
                    *(u32x2_ma*)&kbh[kr][c4] = hv;
                    *(u32x2_ma*)&kbl[kr][c4] = lv;
                }
            }
            __syncthreads();
            #pragma unroll
            for (int es = 0; es < 2; ++es){
                const int eoff = es*32 + lg*8;
                const bf16x8 ah = *(const bf16x8_ma*)&qw_h[lm][ec*64 + eoff];
                const bf16x8 al = *(const bf16x8_ma*)&qw_l[lm][ec*64 + eoff];
                const bf16x8 bh = *(const bf16x8_ma*)&kbh[wv*16 + lm][eoff];
                const bf16x8 bl = *(const bf16x8_ma*)&kbl[wv*16 + lm][eoff];
                sacc = __builtin_amdgcn_mfma_f32_16x16x32_bf16(ah, bh, sacc, 0, 0, 0);
                sacc = __builtin_amdgcn_mfma_f32_16x16x32_bf16(ah, bl, sacc, 0, 0, 0);
                sacc = __builtin_amdgcn_mfma_f32_16x16x32_bf16(al, bh, sacc, 0, 0, 0);
            }
        }

        // ---- scatter scores (C layout: row = lg*4+r, col = lm) + faithful mask ----
        {
            const int key = k0 + wv*16 + lm;
            #pragma unroll
            for (int r = 0; r < 4; ++r)
                s_s[lg*4 + r][wv*16 + lm] = (key < mk) ? sacc[r] : MASK_VALUE;
        }
        __syncthreads();

        // ---- row max + rescale factor (probe-verbatim) ----
        if (tid < 16){
            float tmax = s_s[tid][0];
            for (int c = 1; c < 64; ++c) tmax = fmaxf(tmax, s_s[tid][c]);
            const float mnew = fmaxf(m_s[tid], tmax);
            f_s[tid] = __expf(m_s[tid] - mnew);
            m_s[tid] = mnew;
        }
        __syncthreads();

        // ---- p = exp(s - m) (probe-verbatim) ----
        #pragma unroll
        for (int cc = 0; cc < 4; ++cc)
            p_s[rs][cs+cc] = __expf(s_s[rs][cs+cc] - m_s[rs]);
        __syncthreads();

        // ---- denominator (leaders) + fp32 PV (probe-verbatim, order-preserving unroll) ----
        if (tid < 16){
            float ps = 0.f;
            for (int c = 0; c < 64; ++c) ps += p_s[tid][c];
            l_s[tid] = l_s[tid]*f_s[tid] + ps;
        }
        {
            const float fr = f_s[rp];
            #pragma unroll
            for (int j = 0; j < 32; ++j) o[j] *= fr;
            #pragma unroll 2
            for (int c = 0; c < 64; ++c){
                const float p = p_s[rp][c];
                const float* vrow = V + ((size_t)b*NK + k0 + c)*ND + dp;
                #pragma unroll
                for (int j8 = 0; j8 < 8; ++j8){
                    const f32x4 vv = *(const f32x4_ma*)&vrow[4*j8];
                    o[4*j8+0] += p*vv[0]; o[4*j8+1] += p*vv[1];
                    o[4*j8+2] += p*vv[2]; o[4*j8+3] += p*vv[3];
                }
            }
        }
        __syncthreads();
    }

    // ---- epilogue (probe-verbatim) ----
    {
        const float li = 1.f / l_s[rp];
        #pragma unroll
        for (int j8 = 0; j8 < 8; ++j8){
            f32x4 r;
            r[0] = o[4*j8+0]*li; r[1] = o[4*j8+1]*li;
            r[2] = o[4*j8+2]*li; r[3] = o[4*j8+3]*li;
            *(f32x4_ma*)&O[((size_t)b*NQ + q0 + rp)*ND + dp + 4*j8] = r;
        }
    }
}

extern "C" void kernel_launch(void* const* d_in, const int* in_sizes, int n_in,
                              void* d_out, int out_size, void* d_ws, size_t ws_size,
                              hipStream_t stream)
{
    (void)in_sizes; (void)n_in; (void)out_size; (void)ws_size;
    const float* Qp = (const float*)d_in[0];
    const float* Kp = (const float*)d_in[1];
    const float* Vp = (const float*)d_in[2];
    const float* Wp = (const float*)d_in[3];
    const int*   Mp = (const int*)  d_in[4];
    float* Op = (float*)d_out;

    float* QW = (float*)d_ws;   // 33.5 MB scratch (proven safe in round 4)

    hipLaunchKernelGGL(qw_kernel, dim3(NB*NQ*(ND/4)/256), dim3(256), 0, stream,
                       Qp, Wp, QW);
    hipLaunchKernelGGL(attn_kernel, dim3(NB*(NQ/16)), dim3(256), 0, stream,
                       QW, Kp, Vp, Mp, Op);
}

// Round 6
// 1357.189 us; speedup vs baseline: 8.5959x; 5.8222x over previous
//
#include <hip/hip_runtime.h>

#define NB 8
#define NQ 2048
#define NK 2048
#define ND 512
#define MASK_VALUE (-1e-06f)

typedef __attribute__((ext_vector_type(4))) float f32x4;
typedef __attribute__((ext_vector_type(8))) __bf16 bf16x8;
typedef __attribute__((ext_vector_type(8))) unsigned short u16x8;
typedef __attribute__((ext_vector_type(4))) unsigned int u32x4;
typedef __attribute__((ext_vector_type(2))) unsigned int u32x2;

typedef f32x4  __attribute__((may_alias)) f32x4_ma;
typedef bf16x8 __attribute__((may_alias)) bf16x8_ma;
typedef u32x4  __attribute__((may_alias)) u32x4_ma;
typedef u32x2  __attribute__((may_alias)) u32x2_ma;

__device__ __forceinline__ unsigned short f2bf(float x){
    union { float f; unsigned u; } v; v.f = x;
    unsigned r = v.u + 0x7fffu + ((v.u >> 16) & 1u);
    return (unsigned short)(r >> 16);
}
__device__ __forceinline__ float bf2f(unsigned short h){
    union { unsigned u; float f; } v; v.u = ((unsigned)h) << 16;
    return v.f;
}

// ---------- stage 1 (UNCHANGED, passing): QW = Q @ W, fp32 ----------
__global__ __launch_bounds__(256)
void qw_kernel(const float* __restrict__ Q, const float* __restrict__ W,
               float* __restrict__ QW)
{
    const size_t gid = (size_t)blockIdx.x * 256 + threadIdx.x;
    const int    e4  = ((int)(gid & (ND/4 - 1))) * 4;
    const size_t row = gid >> 7;
    const float* qrow = Q + row * ND;
    float a0=0,a1=0,a2=0,a3=0, b0=0,b1=0,b2=0,b3=0;
    for (int d = 0; d < ND; d += 2){
        const float q0 = qrow[d];
        const float q1 = qrow[d+1];
        const f32x4 w0 = *(const f32x4_ma*)&W[(size_t)d*ND + e4];
        const f32x4 w1 = *(const f32x4_ma*)&W[(size_t)(d+1)*ND + e4];
        a0 += q0*w0[0]; a1 += q0*w0[1]; a2 += q0*w0[2]; a3 += q0*w0[3];
        b0 += q1*w1[0]; b1 += q1*w1[1]; b2 += q1*w1[2]; b3 += q1*w1[3];
    }
    f32x4 r; r[0]=a0+b0; r[1]=a1+b1; r[2]=a2+b2; r[3]=a3+b3;
    *(f32x4_ma*)&QW[row*ND + e4] = r;
}

// ---------- stage 2: QK MFMA (passing) + PV MFMA (the one untested block) ----------
__global__ __launch_bounds__(256)
void attn_kernel(const float* __restrict__ QW, const float* __restrict__ K,
                 const float* __restrict__ V, const int* __restrict__ Mp,
                 float* __restrict__ O)
{
    __shared__ unsigned short qw_h[16][520];
    __shared__ unsigned short qw_l[16][520];
    __shared__ unsigned short kbh[64][72];
    __shared__ unsigned short kbl[64][72];
    __shared__ float s_s[16][68];
    __shared__ float p_s[16][68];
    __shared__ unsigned short p_b[16][72];
    __shared__ float m_s[16], f_s[16], l_s[16];

    const int tid  = threadIdx.x;
    const int lane = tid & 63;
    const int wv   = tid >> 6;
    const int lm   = lane & 15;
    const int lg   = lane >> 4;
    const int b    = blockIdx.x & 7;               // batch -> XCD affinity
    const int q0   = (int)(blockIdx.x >> 3) * 16;

    int mk;
    {   // tolerate int64-encoded masks (values >=1, so odd words all-zero => int64)
        const int odd = Mp[1] | Mp[3] | Mp[5] | Mp[7];
        mk = (odd == 0) ? Mp[2*b] : Mp[b];
    }

    // stage qw tile [16][512] -> hi/lo bf16 planes
    {
        const int r  = tid >> 4;
        const int c0 = (tid & 15) * 32;
        #pragma unroll
        for (int j = 0; j < 8; ++j){
            const f32x4 qv = *(const f32x4_ma*)&QW[((size_t)b*NQ + q0 + r)*ND + c0 + 4*j];
            unsigned short h[4], l[4];
            #pragma unroll
            for (int c = 0; c < 4; ++c){
                h[c] = f2bf(qv[c]);
                l[c] = f2bf(qv[c] - bf2f(h[c]));
            }
            u32x2 hv, lv;
            hv[0] = (unsigned)h[0] | ((unsigned)h[1] << 16);
            hv[1] = (unsigned)h[2] | ((unsigned)h[3] << 16);
            lv[0] = (unsigned)l[0] | ((unsigned)l[1] << 16);
            lv[1] = (unsigned)l[2] | ((unsigned)l[3] << 16);
            *(u32x2_ma*)&qw_h[r][c0 + 4*j] = hv;
            *(u32x2_ma*)&qw_l[r][c0 + 4*j] = lv;
        }
    }
    if (tid < 16){ m_s[tid] = -3.0e38f; l_s[tid] = 0.f; }

    // p ownership (probe-verbatim)
    const int rs = tid & 15;
    const int cs = (tid >> 4) * 4;

    // PV accumulator: wave wv owns d in [wv*128, wv*128+128)
    f32x4 o_acc[8];
    #pragma unroll
    for (int n = 0; n < 8; ++n) o_acc[n] = (f32x4){0.f, 0.f, 0.f, 0.f};

    __syncthreads();

    for (int k0 = 0; k0 < NK; k0 += 64){
        // ---- QK^T via MFMA (UNCHANGED from passing round 5) ----
        f32x4 sacc = {0.f, 0.f, 0.f, 0.f};
        for (int ec = 0; ec < 8; ++ec){
            __syncthreads();
            {   // stage K chunk [64 keys][64 e] -> hi/lo bf16
                const int c4 = (tid & 15) * 4;
                #pragma unroll
                for (int m4 = 0; m4 < 4; ++m4){
                    const int kr = (tid >> 4) + m4*16;
                    const f32x4 kv = *(const f32x4_ma*)&K[((size_t)b*NK + k0 + kr)*ND + ec*64 + c4];
                    unsigned short h[4], l[4];
                    #pragma unroll
                    for (int c = 0; c < 4; ++c){
                        h[c] = f2bf(kv[c]);
                        l[c] = f2bf(kv[c] - bf2f(h[c]));
                    }
                    u32x2 hv, lv;
                    hv[0] = (unsigned)h[0] | ((unsigned)h[1] << 16);
                    hv[1] = (unsigned)h[2] | ((unsigned)h[3] << 16);
                    lv[0] = (unsigned)l[0] | ((unsigned)l[1] << 16);
                    lv[1] = (unsigned)l[2] | ((unsigned)l[3] << 16);
                    *(u32x2_ma*)&kbh[kr][c4] = hv;
                    *(u32x2_ma*)&kbl[kr][c4] = lv;
                }
            }
            __syncthreads();
            #pragma unroll
            for (int es = 0; es < 2; ++es){
                const int eoff = es*32 + lg*8;
                const bf16x8 ah = *(const bf16x8_ma*)&qw_h[lm][ec*64 + eoff];
                const bf16x8 al = *(const bf16x8_ma*)&qw_l[lm][ec*64 + eoff];
                const bf16x8 bh = *(const bf16x8_ma*)&kbh[wv*16 + lm][eoff];
                const bf16x8 bl = *(const bf16x8_ma*)&kbl[wv*16 + lm][eoff];
                sacc = __builtin_amdgcn_mfma_f32_16x16x32_bf16(ah, bh, sacc, 0, 0, 0);
                sacc = __builtin_amdgcn_mfma_f32_16x16x32_bf16(ah, bl, sacc, 0, 0, 0);
                sacc = __builtin_amdgcn_mfma_f32_16x16x32_bf16(al, bh, sacc, 0, 0, 0);
            }
        }

        // ---- scatter scores + faithful mask (UNCHANGED) ----
        {
            const int key = k0 + wv*16 + lm;
            #pragma unroll
            for (int r = 0; r < 4; ++r)
                s_s[lg*4 + r][wv*16 + lm] = (key < mk) ? sacc[r] : MASK_VALUE;
        }
        __syncthreads();

        // ---- row max + rescale factor (UNCHANGED leaders) ----
        if (tid < 16){
            float tmax = s_s[tid][0];
            for (int c = 1; c < 64; ++c) tmax = fmaxf(tmax, s_s[tid][c]);
            const float mnew = fmaxf(m_s[tid], tmax);
            f_s[tid] = __expf(m_s[tid] - mnew);
            m_s[tid] = mnew;
        }
        __syncthreads();

        // ---- p = exp(s - m), plus bf16 copy for PV ----
        #pragma unroll
        for (int cc = 0; cc < 4; ++cc){
            const float p = __expf(s_s[rs][cs+cc] - m_s[rs]);
            p_s[rs][cs+cc] = p;
            p_b[rs][cs+cc] = f2bf(p);
        }
        __syncthreads();

        // ---- denominator (leaders) sums the SAME bf16 p used by PV ----
        if (tid < 16){
            float ps = 0.f;
            for (int c = 0; c < 64; ++c) ps += bf2f(p_b[tid][c]);
            l_s[tid] = l_s[tid]*f_s[tid] + ps;
        }

        // ---- PV via MFMA: the one previously-untested block ----
        {
            float fr4[4];
            #pragma unroll
            for (int r = 0; r < 4; ++r) fr4[r] = f_s[lg*4 + r];
            #pragma unroll
            for (int n = 0; n < 8; ++n)
                #pragma unroll
                for (int r = 0; r < 4; ++r) o_acc[n][r] *= fr4[r];

            const bf16x8 pa0 = *(const bf16x8_ma*)&p_b[lm][lg*8];
            const bf16x8 pa1 = *(const bf16x8_ma*)&p_b[lm][32 + lg*8];
            const float* vbase = V + ((size_t)b*NK + k0)*ND + wv*128 + lm;
            #pragma unroll
            for (int n = 0; n < 8; ++n){
                const float* vp = vbase + n*16;
                #pragma unroll
                for (int ks = 0; ks < 2; ++ks){
                    const int kkb = ks*32 + lg*8;
                    u16x8 vh, vl;
                    #pragma unroll
                    for (int e = 0; e < 8; ++e){
                        const float v = vp[(size_t)(kkb + e)*ND];
                        const unsigned short h = f2bf(v);
                        vh[e] = h;
                        vl[e] = f2bf(v - bf2f(h));
                    }
                    o_acc[n] = __builtin_amdgcn_mfma_f32_16x16x32_bf16(
                                   (ks ? pa1 : pa0), __builtin_bit_cast(bf16x8, vh), o_acc[n], 0, 0, 0);
                    o_acc[n] = __builtin_amdgcn_mfma_f32_16x16x32_bf16(
                                   (ks ? pa1 : pa0), __builtin_bit_cast(bf16x8, vl), o_acc[n], 0, 0, 0);
                }
            }
        }
        __syncthreads();
    }

    // ---- epilogue: normalize rows lg*4+r with the consistent denominator ----
    {
        float li[4];
        #pragma unroll
        for (int r = 0; r < 4; ++r) li[r] = 1.f / l_s[lg*4 + r];
        #pragma unroll
        for (int n = 0; n < 8; ++n)
            #pragma unroll
            for (int r = 0; r < 4; ++r)
                O[((size_t)b*NQ + q0 + lg*4 + r)*ND + wv*128 + n*16 + lm] = o_acc[n][r] * li[r];
    }
}

extern "C" void kernel_launch(void* const* d_in, const int* in_sizes, int n_in,
                              void* d_out, int out_size, void* d_ws, size_t ws_size,
                              hipStream_t stream)
{
    (void)in_sizes; (void)n_in; (void)out_size; (void)ws_size;
    const float* Qp = (const float*)d_in[0];
    const float* Kp = (const float*)d_in[1];
    const float* Vp = (const float*)d_in[2];
    const float* Wp = (const float*)d_in[3];
    const int*   Mp = (const int*)  d_in[4];
    float* Op = (float*)d_out;

    float* QW = (float*)d_ws;   // 33.5 MB scratch (proven safe)

    hipLaunchKernelGGL(qw_kernel, dim3(NB*NQ*(ND/4)/256), dim3(256), 0, stream,
                       Qp, Wp, QW);
    hipLaunchKernelGGL(attn_kernel, dim3(NB*(NQ/16)), dim3(256), 0, stream,
                       QW, Kp, Vp, Mp, Op);
}

// Round 7
// 556.401 us; speedup vs baseline: 20.9674x; 2.4392x over previous
//
#include <hip/hip_runtime.h>

#define NB 8
#define NQ 2048
#define NK 2048
#define ND 512
#define QB 32
#define MASK_VALUE (-1e-06f)
#define PLANE  ((size_t)NB * NK * ND)   // 8,388,608 elems per K/V bf16 plane
#define WPLANE ((size_t)ND * ND)        // 262,144 elems per W bf16 plane

typedef __attribute__((ext_vector_type(4))) float f32x4;
typedef __attribute__((ext_vector_type(8))) __bf16 bf16x8;
typedef __attribute__((ext_vector_type(8))) unsigned short u16x8;
typedef __attribute__((ext_vector_type(4))) unsigned int u32x4;
typedef __attribute__((ext_vector_type(2))) unsigned int u32x2;

typedef f32x4  __attribute__((may_alias)) f32x4_ma;
typedef bf16x8 __attribute__((may_alias)) bf16x8_ma;
typedef u32x4  __attribute__((may_alias)) u32x4_ma;
typedef u32x2  __attribute__((may_alias)) u32x2_ma;

__device__ __forceinline__ unsigned short f2bf(float x){
    union { float f; unsigned u; } v; v.f = x;
    unsigned r = v.u + 0x7fffu + ((v.u >> 16) & 1u);
    return (unsigned short)(r >> 16);
}
__device__ __forceinline__ float bf2f(unsigned short h){
    union { unsigned u; float f; } v; v.u = ((unsigned)h) << 16;
    return v.f;
}

// ---------------- prep 1: K -> hi/lo bf16 planes, layout [b][k][e] ----------------
__global__ __launch_bounds__(256)
void split_k_kernel(const float* __restrict__ K,
                    unsigned short* __restrict__ kh,
                    unsigned short* __restrict__ kl)
{
    const size_t i = ((size_t)blockIdx.x * 256 + threadIdx.x) * 4;
    const f32x4 v = *(const f32x4_ma*)(K + i);
    unsigned short h[4], l[4];
    #pragma unroll
    for (int c = 0; c < 4; ++c){
        h[c] = f2bf(v[c]);
        l[c] = f2bf(v[c] - bf2f(h[c]));
    }
    u32x2 hv, lv;
    hv[0] = (unsigned)h[0] | ((unsigned)h[1] << 16);  hv[1] = (unsigned)h[2] | ((unsigned)h[3] << 16);
    lv[0] = (unsigned)l[0] | ((unsigned)l[1] << 16);  lv[1] = (unsigned)l[2] | ((unsigned)l[3] << 16);
    *(u32x2_ma*)(kh + i) = hv;
    *(u32x2_ma*)(kl + i) = lv;
}

// -------- prep 2: V -> hi/lo bf16 planes TRANSPOSED, layout [b][d][k] --------
__global__ __launch_bounds__(256)
void transpose_split_v_kernel(const float* __restrict__ V,
                              unsigned short* __restrict__ vth,
                              unsigned short* __restrict__ vtl)
{
    __shared__ float t[64][68];
    const int tid = threadIdx.x;
    const int bid = blockIdx.x;
    const int dt  = bid & 7;          // d tile (8 x 64)
    const int kt  = (bid >> 3) & 31;  // k tile (32 x 64)
    const int b   = bid >> 8;         // batch
    {
        const int rr = tid >> 4;
        const int c4 = (tid & 15) * 4;
        #pragma unroll
        for (int m4 = 0; m4 < 4; ++m4){
            const int kr = rr + m4*16;
            *(f32x4_ma*)&t[kr][c4] =
                *(const f32x4_ma*)&V[((size_t)b*NK + kt*64 + kr)*ND + dt*64 + c4];
        }
    }
    __syncthreads();
    {
        const int dr = tid >> 2;          // 0..63 within d tile
        const int kc = (tid & 3) * 16;    // 16 k per thread
        unsigned short hh[16], ll[16];
        #pragma unroll
        for (int j = 0; j < 16; ++j){
            const float v = t[kc + j][dr];
            const unsigned short h = f2bf(v);
            hh[j] = h;
            ll[j] = f2bf(v - bf2f(h));
        }
        u32x4 h0, h1, l0, l1;
        #pragma unroll
        for (int c = 0; c < 4; ++c){
            h0[c] = (unsigned)hh[2*c]   | ((unsigned)hh[2*c+1] << 16);
            h1[c] = (unsigned)hh[8+2*c] | ((unsigned)hh[9+2*c] << 16);
            l0[c] = (unsigned)ll[2*c]   | ((unsigned)ll[2*c+1] << 16);
            l1[c] = (unsigned)ll[8+2*c] | ((unsigned)ll[9+2*c] << 16);
        }
        const size_t dst = ((size_t)b*ND + dt*64 + dr)*NK + kt*64 + kc;
        *(u32x4_ma*)(vth + dst)     = h0;
        *(u32x4_ma*)(vth + dst + 8) = h1;
        *(u32x4_ma*)(vtl + dst)     = l0;
        *(u32x4_ma*)(vtl + dst + 8) = l1;
    }
}

// -------- prep 3: W -> hi/lo bf16 planes TRANSPOSED, layout [e][d] --------
__global__ __launch_bounds__(256)
void transpose_split_w_kernel(const float* __restrict__ W,
                              unsigned short* __restrict__ wth,
                              unsigned short* __restrict__ wtl)
{
    __shared__ float t[64][68];
    const int tid = threadIdx.x;
    const int et  = blockIdx.x & 7;   // e tile
    const int dt  = blockIdx.x >> 3;  // d tile
    {
        const int rr = tid >> 4;
        const int c4 = (tid & 15) * 4;
        #pragma unroll
        for (int m4 = 0; m4 < 4; ++m4){
            const int dr = rr + m4*16;
            *(f32x4_ma*)&t[dr][c4] =
                *(const f32x4_ma*)&W[(size_t)(dt*64 + dr)*ND + et*64 + c4];
        }
    }
    __syncthreads();
    {
        const int er = tid >> 2;          // 0..63 within e tile
        const int dc = (tid & 3) * 16;    // 16 d per thread
        unsigned short hh[16], ll[16];
        #pragma unroll
        for (int j = 0; j < 16; ++j){
            const float v = t[dc + j][er];
            const unsigned short h = f2bf(v);
            hh[j] = h;
            ll[j] = f2bf(v - bf2f(h));
        }
        u32x4 h0, h1, l0, l1;
        #pragma unroll
        for (int c = 0; c < 4; ++c){
            h0[c] = (unsigned)hh[2*c]   | ((unsigned)hh[2*c+1] << 16);
            h1[c] = (unsigned)hh[8+2*c] | ((unsigned)hh[9+2*c] << 16);
            l0[c] = (unsigned)ll[2*c]   | ((unsigned)ll[2*c+1] << 16);
            l1[c] = (unsigned)ll[8+2*c] | ((unsigned)ll[9+2*c] << 16);
        }
        const size_t dst = (size_t)(et*64 + er)*ND + dt*64 + dc;
        *(u32x4_ma*)(wth + dst)     = h0;
        *(u32x4_ma*)(wth + dst + 8) = h1;
        *(u32x4_ma*)(wtl + dst)     = l0;
        *(u32x4_ma*)(wtl + dst + 8) = l1;
    }
}

// ---------------- main fused kernel: QW (MFMA) + flash attention ----------------
__global__ __launch_bounds__(256, 2)
void attn_kernel(const float* __restrict__ Qp, const int* __restrict__ Mp,
                 const unsigned short* __restrict__ Kh, const unsigned short* __restrict__ Kl,
                 const unsigned short* __restrict__ Vth, const unsigned short* __restrict__ Vtl,
                 const unsigned short* __restrict__ Wth, const unsigned short* __restrict__ Wtl,
                 float* __restrict__ Op)
{
    __shared__ unsigned short qw_h[QB][520];
    __shared__ unsigned short qw_l[QB][520];
    __shared__ unsigned short p_b[QB][72];
    __shared__ float wredA[QB][4];
    __shared__ float wredB[QB][4];

    const int tid  = threadIdx.x;
    const int lane = tid & 63;
    const int wv   = tid >> 6;              // wave 0..3
    const int lm   = lane & 15;             // MFMA lane%16
    const int lg   = lane >> 4;             // MFMA lane group 0..3
    const int b    = blockIdx.x & 7;        // batch -> XCD affinity
    const int q0   = (int)(blockIdx.x >> 3) * QB;

    int mk;
    {   // tolerate int64-encoded masks (values >=1, so odd words all-zero => int64)
        const int odd = Mp[1] | Mp[3] | Mp[5] | Mp[7];
        mk = (odd == 0) ? Mp[2*b] : Mp[b];
    }

    // ===== Phase 1: qw[32][512] = Q_tile @ W via MFMA (hi/lo 3-term) =====
    {
        f32x4 acc[2][8];
        #pragma unroll
        for (int m2 = 0; m2 < 2; ++m2)
            #pragma unroll
            for (int n2 = 0; n2 < 8; ++n2) acc[m2][n2] = (f32x4){0.f,0.f,0.f,0.f};

        for (int w = 0; w < 16; ++w){      // K-window over d (32 per window)
            bf16x8 aH[2], aL[2];
            #pragma unroll
            for (int m2 = 0; m2 < 2; ++m2){
                const float* qp = Qp + ((size_t)b*NQ + q0 + m2*16 + lm)*ND + w*32 + lg*8;
                const f32x4 qa = *(const f32x4_ma*)qp;
                const f32x4 qb = *(const f32x4_ma*)(qp + 4);
                u16x8 hh, ll;
                #pragma unroll
                for (int c = 0; c < 4; ++c){
                    const unsigned short h = f2bf(qa[c]);
                    hh[c] = h; ll[c] = f2bf(qa[c] - bf2f(h));
                }
                #pragma unroll
                for (int c = 0; c < 4; ++c){
                    const unsigned short h = f2bf(qb[c]);
                    hh[4+c] = h; ll[4+c] = f2bf(qb[c] - bf2f(h));
                }
                aH[m2] = __builtin_bit_cast(bf16x8, hh);
                aL[m2] = __builtin_bit_cast(bf16x8, ll);
            }
            const size_t wbase = (size_t)(wv*16 + lm)*ND + w*32 + lg*8;
            #pragma unroll
            for (int n2 = 0; n2 < 8; ++n2){
                const size_t wrow = wbase + (size_t)n2*64*ND;
                const bf16x8 bh = *(const bf16x8_ma*)(Wth + wrow);
                const bf16x8 bl = *(const bf16x8_ma*)(Wtl + wrow);
                #pragma unroll
                for (int m2 = 0; m2 < 2; ++m2){
                    acc[m2][n2] = __builtin_amdgcn_mfma_f32_16x16x32_bf16(aH[m2], bh, acc[m2][n2], 0,0,0);
                    acc[m2][n2] = __builtin_amdgcn_mfma_f32_16x16x32_bf16(aH[m2], bl, acc[m2][n2], 0,0,0);
                    acc[m2][n2] = __builtin_amdgcn_mfma_f32_16x16x32_bf16(aL[m2], bh, acc[m2][n2], 0,0,0);
                }
            }
        }
        // C-scatter (row = lg*4+r, col = lm; m89-verified) + hi/lo split into LDS
        #pragma unroll
        for (int m2 = 0; m2 < 2; ++m2)
            #pragma unroll
            for (int n2 = 0; n2 < 8; ++n2)
                #pragma unroll
                for (int r = 0; r < 4; ++r){
                    const float v = acc[m2][n2][r];
                    const unsigned short h = f2bf(v);
                    const unsigned short l = f2bf(v - bf2f(h));
                    const int row = m2*16 + lg*4 + r;
                    const int col = n2*64 + wv*16 + lm;
                    qw_h[row][col] = h;
                    qw_l[row][col] = l;
                }
    }
    __syncthreads();

    // ===== Phase 2: flash loop, register online-softmax, 2 row-sets =====
    float m_run[2][4], l_run[2][4];
    #pragma unroll
    for (int s = 0; s < 2; ++s)
        #pragma unroll
        for (int r = 0; r < 4; ++r){ m_run[s][r] = -3.0e38f; l_run[s][r] = 0.f; }

    f32x4 o_acc[2][8];
    #pragma unroll
    for (int s = 0; s < 2; ++s)
        #pragma unroll
        for (int n = 0; n < 8; ++n) o_acc[s][n] = (f32x4){0.f,0.f,0.f,0.f};

    const unsigned short* khb = Kh + ((size_t)b*NK + wv*16 + lm)*ND;
    const unsigned short* klb = Kl + ((size_t)b*NK + wv*16 + lm)*ND;
    const size_t vbase = ((size_t)b*ND + wv*128 + lm)*NK + lg*8;

    for (int k0 = 0; k0 < NK; k0 += 64){
        const size_t koff = (size_t)k0 * ND;

        // ---- QK^T: wave wv owns key-cols [wv*16, +16); B-frags shared by both row-sets ----
        f32x4 sacc[2];
        sacc[0] = (f32x4){0.f,0.f,0.f,0.f};
        sacc[1] = (f32x4){0.f,0.f,0.f,0.f};
        #pragma unroll
        for (int w = 0; w < 16; ++w){
            const int eoff = w*32 + lg*8;
            const bf16x8 bh = *(const bf16x8_ma*)(khb + koff + eoff);
            const bf16x8 bl = *(const bf16x8_ma*)(klb + koff + eoff);
            #pragma unroll
            for (int s = 0; s < 2; ++s){
                const bf16x8 aH = *(const bf16x8_ma*)&qw_h[s*16 + lm][eoff];
                const bf16x8 aL = *(const bf16x8_ma*)&qw_l[s*16 + lm][eoff];
                sacc[s] = __builtin_amdgcn_mfma_f32_16x16x32_bf16(aH, bh, sacc[s], 0,0,0);
                sacc[s] = __builtin_amdgcn_mfma_f32_16x16x32_bf16(aH, bl, sacc[s], 0,0,0);
                sacc[s] = __builtin_amdgcn_mfma_f32_16x16x32_bf16(aL, bh, sacc[s], 0,0,0);
            }
        }

        // ---- faithful mask (lane-local: this lane's key is k0 + wv*16 + lm) ----
        const bool inval = (k0 + wv*16 + lm) >= mk;
        float sv[2][4];
        #pragma unroll
        for (int s = 0; s < 2; ++s)
            #pragma unroll
            for (int r = 0; r < 4; ++r) sv[s][r] = inval ? MASK_VALUE : sacc[s][r];

        // ---- row max: reduce over 16 key-lanes, then cross-wave via LDS ----
        float pm[2][4];
        #pragma unroll
        for (int s = 0; s < 2; ++s)
            #pragma unroll
            for (int r = 0; r < 4; ++r) pm[s][r] = sv[s][r];
        #pragma unroll
        for (int off = 1; off < 16; off <<= 1)
            #pragma unroll
            for (int s = 0; s < 2; ++s)
                #pragma unroll
                for (int r = 0; r < 4; ++r)
                    pm[s][r] = fmaxf(pm[s][r], __shfl_xor(pm[s][r], off, 64));
        if (lm == 0){
            #pragma unroll
            for (int s = 0; s < 2; ++s)
                #pragma unroll
                for (int r = 0; r < 4; ++r) wredA[s*16 + lg*4 + r][wv] = pm[s][r];
        }
        __syncthreads();

        float fsc[2][4], ps[2][4];
        #pragma unroll
        for (int s = 0; s < 2; ++s)
            #pragma unroll
            for (int r = 0; r < 4; ++r){
                const int row = s*16 + lg*4 + r;
                const f32x4 g4 = *(const f32x4_ma*)&wredA[row][0];
                const float gm = fmaxf(fmaxf(g4[0], g4[1]), fmaxf(g4[2], g4[3]));
                const float mnew = fmaxf(m_run[s][r], gm);
                fsc[s][r] = __expf(m_run[s][r] - mnew);
                m_run[s][r] = mnew;
                const float p = __expf(sv[s][r] - mnew);
                const unsigned short pb = f2bf(p);
                ps[s][r] = bf2f(pb);                 // denominator sums bf16-rounded p
                p_b[row][wv*16 + lm] = pb;           // transpose bounce for PV A-frag
            }
        #pragma unroll
        for (int off = 1; off < 16; off <<= 1)
            #pragma unroll
            for (int s = 0; s < 2; ++s)
                #pragma unroll
                for (int r = 0; r < 4; ++r)
                    ps[s][r] += __shfl_xor(ps[s][r], off, 64);
        if (lm == 0){
            #pragma unroll
            for (int s = 0; s < 2; ++s)
                #pragma unroll
                for (int r = 0; r < 4; ++r) wredB[s*16 + lg*4 + r][wv] = ps[s][r];
        }
        __syncthreads();
        #pragma unroll
        for (int s = 0; s < 2; ++s)
            #pragma unroll
            for (int r = 0; r < 4; ++r){
                const f32x4 s4 = *(const f32x4_ma*)&wredB[s*16 + lg*4 + r][0];
                l_run[s][r] = l_run[s][r]*fsc[s][r] + ((s4[0] + s4[1]) + (s4[2] + s4[3]));
            }

        // ---- PV: rescale, then o += P @ V; V B-frags shared by both row-sets ----
        #pragma unroll
        for (int s = 0; s < 2; ++s)
            #pragma unroll
            for (int n = 0; n < 8; ++n)
                #pragma unroll
                for (int r = 0; r < 4; ++r) o_acc[s][n][r] *= fsc[s][r];

        bf16x8 pa[2][2];
        #pragma unroll
        for (int s = 0; s < 2; ++s){
            pa[s][0] = *(const bf16x8_ma*)&p_b[s*16 + lm][lg*8];
            pa[s][1] = *(const bf16x8_ma*)&p_b[s*16 + lm][32 + lg*8];
        }
        #pragma unroll
        for (int n = 0; n < 8; ++n){
            const size_t roff = vbase + (size_t)n*16*NK + k0;
            const bf16x8 vh0 = *(const bf16x8_ma*)(Vth + roff);
            const bf16x8 vl0 = *(const bf16x8_ma*)(Vtl + roff);
            const bf16x8 vh1 = *(const bf16x8_ma*)(Vth + roff + 32);
            const bf16x8 vl1 = *(const bf16x8_ma*)(Vtl + roff + 32);
            #pragma unroll
            for (int s = 0; s < 2; ++s){
                o_acc[s][n] = __builtin_amdgcn_mfma_f32_16x16x32_bf16(pa[s][0], vh0, o_acc[s][n], 0,0,0);
                o_acc[s][n] = __builtin_amdgcn_mfma_f32_16x16x32_bf16(pa[s][0], vl0, o_acc[s][n], 0,0,0);
                o_acc[s][n] = __builtin_amdgcn_mfma_f32_16x16x32_bf16(pa[s][1], vh1, o_acc[s][n], 0,0,0);
                o_acc[s][n] = __builtin_amdgcn_mfma_f32_16x16x32_bf16(pa[s][1], vl1, o_acc[s][n], 0,0,0);
            }
        }
    }

    // ===== epilogue: normalize with the consistent denominator =====
    {
        float li[2][4];
        #pragma unroll
        for (int s = 0; s < 2; ++s)
            #pragma unroll
            for (int r = 0; r < 4; ++r) li[s][r] = 1.f / l_run[s][r];
        #pragma unroll
        for (int s = 0; s < 2; ++s)
            #pragma unroll
            for (int n = 0; n < 8; ++n)
                #pragma unroll
                for (int r = 0; r < 4; ++r)
                    Op[((size_t)b*NQ + q0 + s*16 + lg*4 + r)*ND + wv*128 + n*16 + lm]
                        = o_acc[s][n][r] * li[s][r];
    }
}

extern "C" void kernel_launch(void* const* d_in, const int* in_sizes, int n_in,
                              void* d_out, int out_size, void* d_ws, size_t ws_size,
                              hipStream_t stream)
{
    (void)in_sizes; (void)n_in; (void)out_size; (void)ws_size;
    const float* Qp = (const float*)d_in[0];
    const float* Kp = (const float*)d_in[1];
    const float* Vp = (const float*)d_in[2];
    const float* Wp = (const float*)d_in[3];
    const int*   Mp = (const int*)  d_in[4];
    float* Op = (float*)d_out;

    unsigned short* wsu = (unsigned short*)d_ws;   // 68.2 MB total (80 MB evidenced in r3)
    unsigned short* Kh  = wsu;
    unsigned short* Kl  = wsu + PLANE;
    unsigned short* Vth = wsu + 2*PLANE;
    unsigned short* Vtl = wsu + 3*PLANE;
    unsigned short* Wth = wsu + 4*PLANE;
    unsigned short* Wtl = wsu + 4*PLANE + WPLANE;

    hipLaunchKernelGGL(split_k_kernel, dim3(PLANE/1024), dim3(256), 0, stream,
                       Kp, Kh, Kl);
    hipLaunchKernelGGL(transpose_split_v_kernel, dim3(NB*32*8), dim3(256), 0, stream,
                       Vp, Vth, Vtl);
    hipLaunchKernelGGL(transpose_split_w_kernel, dim3(64), dim3(256), 0, stream,
                       Wp, Wth, Wtl);
    hipLaunchKernelGGL(attn_kernel, dim3(NB*(NQ/QB)), dim3(256), 0, stream,
                       Qp, Mp, Kh, Kl, Vth, Vtl, Wth, Wtl, Op);
}

// Round 8
// 459.153 us; speedup vs baseline: 25.4082x; 1.2118x over previous
//
#include <hip/hip_runtime.h>

#define NB 8
#define NQ 2048
#define NK 2048
#define ND 512
#define QB 32
#define KB 128
#define MASK_VALUE (-1e-06f)
#define PLANE  ((size_t)NB * NK * ND)   // 8,388,608 elems per K/V plane
#define WPLANE ((size_t)ND * ND)        // 262,144 elems per W plane

typedef __attribute__((ext_vector_type(4))) float f32x4;
typedef __attribute__((ext_vector_type(8))) __bf16 bf16x8;
typedef __attribute__((ext_vector_type(8))) _Float16 f16x8;
typedef __attribute__((ext_vector_type(8))) unsigned short u16x8;
typedef __attribute__((ext_vector_type(4))) unsigned int u32x4;
typedef __attribute__((ext_vector_type(2))) unsigned int u32x2;

typedef f32x4  __attribute__((may_alias)) f32x4_ma;
typedef bf16x8 __attribute__((may_alias)) bf16x8_ma;
typedef f16x8  __attribute__((may_alias)) f16x8_ma;
typedef u32x4  __attribute__((may_alias)) u32x4_ma;
typedef u32x2  __attribute__((may_alias)) u32x2_ma;

__device__ __forceinline__ unsigned short f2bf(float x){
    union { float f; unsigned u; } v; v.f = x;
    unsigned r = v.u + 0x7fffu + ((v.u >> 16) & 1u);
    return (unsigned short)(r >> 16);
}
__device__ __forceinline__ float bf2f(unsigned short h){
    union { unsigned u; float f; } v; v.u = ((unsigned)h) << 16;
    return v.f;
}

// ---------------- prep 1: K -> hi/lo bf16 planes, layout [b][k][e] ----------------
__global__ __launch_bounds__(256)
void split_k_kernel(const float* __restrict__ K,
                    unsigned short* __restrict__ kh,
                    unsigned short* __restrict__ kl)
{
    const size_t i = ((size_t)blockIdx.x * 256 + threadIdx.x) * 4;
    const f32x4 v = *(const f32x4_ma*)(K + i);
    unsigned short h[4], l[4];
    #pragma unroll
    for (int c = 0; c < 4; ++c){
        h[c] = f2bf(v[c]);
        l[c] = f2bf(v[c] - bf2f(h[c]));
    }
    u32x2 hv, lv;
    hv[0] = (unsigned)h[0] | ((unsigned)h[1] << 16);  hv[1] = (unsigned)h[2] | ((unsigned)h[3] << 16);
    lv[0] = (unsigned)l[0] | ((unsigned)l[1] << 16);  lv[1] = (unsigned)l[2] | ((unsigned)l[3] << 16);
    *(u32x2_ma*)(kh + i) = hv;
    *(u32x2_ma*)(kl + i) = lv;
}

// -------- prep 2: V -> single fp16 plane TRANSPOSED, layout [b][d][k] --------
__global__ __launch_bounds__(256)
void transpose_v_f16_kernel(const float* __restrict__ V,
                            _Float16* __restrict__ vt)
{
    __shared__ float t[64][68];
    const int tid = threadIdx.x;
    const int bid = blockIdx.x;
    const int dt  = bid & 7;          // d tile (8 x 64)
    const int kt  = (bid >> 3) & 31;  // k tile (32 x 64)
    const int b   = bid >> 8;         // batch
    {
        const int rr = tid >> 4;
        const int c4 = (tid & 15) * 4;
        #pragma unroll
        for (int m4 = 0; m4 < 4; ++m4){
            const int kr = rr + m4*16;
            *(f32x4_ma*)&t[kr][c4] =
                *(const f32x4_ma*)&V[((size_t)b*NK + kt*64 + kr)*ND + dt*64 + c4];
        }
    }
    __syncthreads();
    {
        const int dr = tid >> 2;          // 0..63 within d tile
        const int kc = (tid & 3) * 16;    // 16 k per thread
        f16x8 v0, v1;
        #pragma unroll
        for (int j = 0; j < 8; ++j) v0[j] = (_Float16)t[kc + j][dr];
        #pragma unroll
        for (int j = 0; j < 8; ++j) v1[j] = (_Float16)t[kc + 8 + j][dr];
        const size_t dst = ((size_t)b*ND + dt*64 + dr)*NK + kt*64 + kc;
        *(f16x8_ma*)(vt + dst)     = v0;
        *(f16x8_ma*)(vt + dst + 8) = v1;
    }
}

// -------- prep 3: W -> hi/lo bf16 planes TRANSPOSED, layout [e][d] --------
__global__ __launch_bounds__(256)
void transpose_split_w_kernel(const float* __restrict__ W,
                              unsigned short* __restrict__ wth,
                              unsigned short* __restrict__ wtl)
{
    __shared__ float t[64][68];
    const int tid = threadIdx.x;
    const int et  = blockIdx.x & 7;   // e tile
    const int dt  = blockIdx.x >> 3;  // d tile
    {
        const int rr = tid >> 4;
        const int c4 = (tid & 15) * 4;
        #pragma unroll
        for (int m4 = 0; m4 < 4; ++m4){
            const int dr = rr + m4*16;
            *(f32x4_ma*)&t[dr][c4] =
                *(const f32x4_ma*)&W[(size_t)(dt*64 + dr)*ND + et*64 + c4];
        }
    }
    __syncthreads();
    {
        const int er = tid >> 2;
        const int dc = (tid & 3) * 16;
        unsigned short hh[16], ll[16];
        #pragma unroll
        for (int j = 0; j < 16; ++j){
            const float v = t[dc + j][er];
            const unsigned short h = f2bf(v);
            hh[j] = h;
            ll[j] = f2bf(v - bf2f(h));
        }
        u32x4 h0, h1, l0, l1;
        #pragma unroll
        for (int c = 0; c < 4; ++c){
            h0[c] = (unsigned)hh[2*c]   | ((unsigned)hh[2*c+1] << 16);
            h1[c] = (unsigned)hh[8+2*c] | ((unsigned)hh[9+2*c] << 16);
            l0[c] = (unsigned)ll[2*c]   | ((unsigned)ll[2*c+1] << 16);
            l1[c] = (unsigned)ll[8+2*c] | ((unsigned)ll[9+2*c] << 16);
        }
        const size_t dst = (size_t)(et*64 + er)*ND + dt*64 + dc;
        *(u32x4_ma*)(wth + dst)     = h0;
        *(u32x4_ma*)(wth + dst + 8) = h1;
        *(u32x4_ma*)(wtl + dst)     = l0;
        *(u32x4_ma*)(wtl + dst + 8) = l1;
    }
}

// ---------------- main fused kernel: 8 waves, KB=128, fp16 PV ----------------
__global__ __launch_bounds__(512, 4)
void attn_kernel(const float* __restrict__ Qp, const int* __restrict__ Mp,
                 const unsigned short* __restrict__ Kh, const unsigned short* __restrict__ Kl,
                 const _Float16* __restrict__ Vt,
                 const unsigned short* __restrict__ Wth, const unsigned short* __restrict__ Wtl,
                 float* __restrict__ Op)
{
    __shared__ unsigned short qw_h[QB][520];
    __shared__ unsigned short qw_l[QB][520];
    __shared__ _Float16 p_b[QB][136];
    __shared__ float wredA[QB][8];
    __shared__ float wredB[QB][8];

    const int tid  = threadIdx.x;
    const int lane = tid & 63;
    const int wv   = tid >> 6;              // wave 0..7
    const int lm   = lane & 15;             // MFMA lane%16
    const int lg   = lane >> 4;             // MFMA lane group 0..3
    const int b    = blockIdx.x & 7;        // batch -> XCD affinity
    const int q0   = (int)(blockIdx.x >> 3) * QB;

    int mk;
    {   // tolerate int64-encoded masks (values >=1, so odd words all-zero => int64)
        const int odd = Mp[1] | Mp[3] | Mp[5] | Mp[7];
        mk = (odd == 0) ? Mp[2*b] : Mp[b];
    }

    // ===== Phase 1: qw[32][512] = Q_tile @ W via MFMA; wave wv owns cols [wv*64,+64) =====
    {
        f32x4 acc[2][4];
        #pragma unroll
        for (int m2 = 0; m2 < 2; ++m2)
            #pragma unroll
            for (int n2 = 0; n2 < 4; ++n2) acc[m2][n2] = (f32x4){0.f,0.f,0.f,0.f};

        for (int w = 0; w < 16; ++w){      // K-window over d (32 per window)
            bf16x8 aH[2], aL[2];
            #pragma unroll
            for (int m2 = 0; m2 < 2; ++m2){
                const float* qp = Qp + ((size_t)b*NQ + q0 + m2*16 + lm)*ND + w*32 + lg*8;
                const f32x4 qa = *(const f32x4_ma*)qp;
                const f32x4 qb = *(const f32x4_ma*)(qp + 4);
                u16x8 hh, ll;
                #pragma unroll
                for (int c = 0; c < 4; ++c){
                    const unsigned short h = f2bf(qa[c]);
                    hh[c] = h; ll[c] = f2bf(qa[c] - bf2f(h));
                }
                #pragma unroll
                for (int c = 0; c < 4; ++c){
                    const unsigned short h = f2bf(qb[c]);
                    hh[4+c] = h; ll[4+c] = f2bf(qb[c] - bf2f(h));
                }
                aH[m2] = __builtin_bit_cast(bf16x8, hh);
                aL[m2] = __builtin_bit_cast(bf16x8, ll);
            }
            #pragma unroll
            for (int n2 = 0; n2 < 4; ++n2){
                const size_t wrow = (size_t)(wv*64 + n2*16 + lm)*ND + w*32 + lg*8;
                const bf16x8 bh = *(const bf16x8_ma*)(Wth + wrow);
                const bf16x8 bl = *(const bf16x8_ma*)(Wtl + wrow);
                #pragma unroll
                for (int m2 = 0; m2 < 2; ++m2){
                    acc[m2][n2] = __builtin_amdgcn_mfma_f32_16x16x32_bf16(aH[m2], bh, acc[m2][n2], 0,0,0);
                    acc[m2][n2] = __builtin_amdgcn_mfma_f32_16x16x32_bf16(aH[m2], bl, acc[m2][n2], 0,0,0);
                    acc[m2][n2] = __builtin_amdgcn_mfma_f32_16x16x32_bf16(aL[m2], bh, acc[m2][n2], 0,0,0);
                }
            }
        }
        // C-scatter (row = lg*4+r, col = lm; m89-verified) + hi/lo split into LDS
        #pragma unroll
        for (int m2 = 0; m2 < 2; ++m2)
            #pragma unroll
            for (int n2 = 0; n2 < 4; ++n2)
                #pragma unroll
                for (int r = 0; r < 4; ++r){
                    const float v = acc[m2][n2][r];
                    const unsigned short h = f2bf(v);
                    const unsigned short l = f2bf(v - bf2f(h));
                    const int row = m2*16 + lg*4 + r;
                    const int col = wv*64 + n2*16 + lm;
                    qw_h[row][col] = h;
                    qw_l[row][col] = l;
                }
    }
    __syncthreads();

    // ===== Phase 2: flash loop over 16 tiles of 128 keys =====
    float m_run[2][4], l_run[2][4];
    #pragma unroll
    for (int s = 0; s < 2; ++s)
        #pragma unroll
        for (int r = 0; r < 4; ++r){ m_run[s][r] = -3.0e38f; l_run[s][r] = 0.f; }

    f32x4 o_acc[2][4];
    #pragma unroll
    for (int s = 0; s < 2; ++s)
        #pragma unroll
        for (int n = 0; n < 4; ++n) o_acc[s][n] = (f32x4){0.f,0.f,0.f,0.f};

    const unsigned short* khb = Kh + ((size_t)b*NK + wv*16 + lm)*ND;
    const unsigned short* klb = Kl + ((size_t)b*NK + wv*16 + lm)*ND;
    const size_t vbase = ((size_t)b*ND + wv*64 + lm)*NK + lg*8;

    for (int k0 = 0; k0 < NK; k0 += KB){
        const size_t koff = (size_t)k0 * ND;

        // ---- QK^T: wave wv owns key-cols [wv*16,+16) of the 128-tile ----
        f32x4 sacc[2];
        sacc[0] = (f32x4){0.f,0.f,0.f,0.f};
        sacc[1] = (f32x4){0.f,0.f,0.f,0.f};
        #pragma unroll
        for (int w = 0; w < 16; ++w){
            const int eoff = w*32 + lg*8;
            const bf16x8 bh = *(const bf16x8_ma*)(khb + koff + eoff);
            const bf16x8 bl = *(const bf16x8_ma*)(klb + koff + eoff);
            #pragma unroll
            for (int s = 0; s < 2; ++s){
                const bf16x8 aH = *(const bf16x8_ma*)&qw_h[s*16 + lm][eoff];
                const bf16x8 aL = *(const bf16x8_ma*)&qw_l[s*16 + lm][eoff];
                sacc[s] = __builtin_amdgcn_mfma_f32_16x16x32_bf16(aH, bh, sacc[s], 0,0,0);
                sacc[s] = __builtin_amdgcn_mfma_f32_16x16x32_bf16(aH, bl, sacc[s], 0,0,0);
                sacc[s] = __builtin_amdgcn_mfma_f32_16x16x32_bf16(aL, bh, sacc[s], 0,0,0);
            }
        }

        // ---- faithful mask (lane-local: this lane's key is k0 + wv*16 + lm) ----
        const bool inval = (k0 + wv*16 + lm) >= mk;
        float sv[2][4];
        #pragma unroll
        for (int s = 0; s < 2; ++s)
            #pragma unroll
            for (int r = 0; r < 4; ++r) sv[s][r] = inval ? MASK_VALUE : sacc[s][r];

        // ---- row max: 16-lane shuffle reduce, then cross-wave (8 waves) via LDS ----
        float pm[2][4];
        #pragma unroll
        for (int s = 0; s < 2; ++s)
            #pragma unroll
            for (int r = 0; r < 4; ++r) pm[s][r] = sv[s][r];
        #pragma unroll
        for (int off = 1; off < 16; off <<= 1)
            #pragma unroll
            for (int s = 0; s < 2; ++s)
                #pragma unroll
                for (int r = 0; r < 4; ++r)
                    pm[s][r] = fmaxf(pm[s][r], __shfl_xor(pm[s][r], off, 64));
        if (lm == 0){
            #pragma unroll
            for (int s = 0; s < 2; ++s)
                #pragma unroll
                for (int r = 0; r < 4; ++r) wredA[s*16 + lg*4 + r][wv] = pm[s][r];
        }
        __syncthreads();

        float fsc[2][4], ps[2][4];
        #pragma unroll
        for (int s = 0; s < 2; ++s)
            #pragma unroll
            for (int r = 0; r < 4; ++r){
                const int row = s*16 + lg*4 + r;
                const f32x4 g0 = *(const f32x4_ma*)&wredA[row][0];
                const f32x4 g1 = *(const f32x4_ma*)&wredA[row][4];
                const float gm = fmaxf(fmaxf(fmaxf(g0[0], g0[1]), fmaxf(g0[2], g0[3])),
                                       fmaxf(fmaxf(g1[0], g1[1]), fmaxf(g1[2], g1[3])));
                const float mnew = fmaxf(m_run[s][r], gm);
                fsc[s][r] = __expf(m_run[s][r] - mnew);
                m_run[s][r] = mnew;
                const float p = __expf(sv[s][r] - mnew);
                const _Float16 ph = (_Float16)p;     // fp16-rounded p used by BOTH num & denom
                ps[s][r] = (float)ph;
                p_b[row][wv*16 + lm] = ph;           // transpose bounce for PV A-frag
            }
        #pragma unroll
        for (int off = 1; off < 16; off <<= 1)
            #pragma unroll
            for (int s = 0; s < 2; ++s)
                #pragma unroll
                for (int r = 0; r < 4; ++r)
                    ps[s][r] += __shfl_xor(ps[s][r], off, 64);
        if (lm == 0){
            #pragma unroll
            for (int s = 0; s < 2; ++s)
                #pragma unroll
                for (int r = 0; r < 4; ++r) wredB[s*16 + lg*4 + r][wv] = ps[s][r];
        }
        __syncthreads();
        #pragma unroll
        for (int s = 0; s < 2; ++s)
            #pragma unroll
            for (int r = 0; r < 4; ++r){
                const f32x4 s0 = *(const f32x4_ma*)&wredB[s*16 + lg*4 + r][0];
                const f32x4 s1 = *(const f32x4_ma*)&wredB[s*16 + lg*4 + r][4];
                l_run[s][r] = l_run[s][r]*fsc[s][r]
                            + (((s0[0]+s0[1]) + (s0[2]+s0[3])) + ((s1[0]+s1[1]) + (s1[2]+s1[3])));
            }

        // ---- PV (fp16): rescale, then o += P @ V on wave's 64 d-cols ----
        #pragma unroll
        for (int s = 0; s < 2; ++s)
            #pragma unroll
            for (int n = 0; n < 4; ++n)
                #pragma unroll
                for (int r = 0; r < 4; ++r) o_acc[s][n][r] *= fsc[s][r];

        f16x8 pa[2][4];
        #pragma unroll
        for (int s = 0; s < 2; ++s)
            #pragma unroll
            for (int kb = 0; kb < 4; ++kb)
                pa[s][kb] = *(const f16x8_ma*)&p_b[s*16 + lm][kb*32 + lg*8];
        #pragma unroll
        for (int n = 0; n < 4; ++n){
            const size_t roff = vbase + (size_t)n*16*NK + k0;
            #pragma unroll
            for (int kb = 0; kb < 4; ++kb){
                const f16x8 vv = *(const f16x8_ma*)(Vt + roff + kb*32);
                #pragma unroll
                for (int s = 0; s < 2; ++s)
                    o_acc[s][n] = __builtin_amdgcn_mfma_f32_16x16x32_f16(pa[s][kb], vv, o_acc[s][n], 0,0,0);
            }
        }
    }

    // ===== epilogue: normalize with the consistent denominator =====
    {
        float li[2][4];
        #pragma unroll
        for (int s = 0; s < 2; ++s)
            #pragma unroll
            for (int r = 0; r < 4; ++r) li[s][r] = 1.f / l_run[s][r];
        #pragma unroll
        for (int s = 0; s < 2; ++s)
            #pragma unroll
            for (int n = 0; n < 4; ++n)
                #pragma unroll
                for (int r = 0; r < 4; ++r)
                    Op[((size_t)b*NQ + q0 + s*16 + lg*4 + r)*ND + wv*64 + n*16 + lm]
                        = o_acc[s][n][r] * li[s][r];
    }
}

extern "C" void kernel_launch(void* const* d_in, const int* in_sizes, int n_in,
                              void* d_out, int out_size, void* d_ws, size_t ws_size,
                              hipStream_t stream)
{
    (void)in_sizes; (void)n_in; (void)out_size; (void)ws_size;
    const float* Qp = (const float*)d_in[0];
    const float* Kp = (const float*)d_in[1];
    const float* Vp = (const float*)d_in[2];
    const float* Wp = (const float*)d_in[3];
    const int*   Mp = (const int*)  d_in[4];
    float* Op = (float*)d_out;

    unsigned short* wsu = (unsigned short*)d_ws;   // 51.4 MB total (< 68 MB proven)
    unsigned short* Kh  = wsu;
    unsigned short* Kl  = wsu + PLANE;
    _Float16*       Vt  = (_Float16*)(wsu + 2*PLANE);
    unsigned short* Wth = wsu + 3*PLANE;
    unsigned short* Wtl = wsu + 3*PLANE + WPLANE;

    hipLaunchKernelGGL(split_k_kernel, dim3(PLANE/1024), dim3(256), 0, stream,
                       Kp, Kh, Kl);
    hipLaunchKernelGGL(transpose_v_f16_kernel, dim3(NB*32*8), dim3(256), 0, stream,
                       Vp, Vt);
    hipLaunchKernelGGL(transpose_split_w_kernel, dim3(64), dim3(256), 0, stream,
                       Wp, Wth, Wtl);
    hipLaunchKernelGGL(attn_kernel, dim3(NB*(NQ/QB)), dim3(512), 0, stream,
                       Qp, Mp, Kh, Kl, Vt, Wth, Wtl, Op);
}

// Round 9
// 361.715 us; speedup vs baseline: 32.2527x; 1.2694x over previous
//
#include <hip/hip_runtime.h>

#define NB 8
#define NQ 2048
#define NK 2048
#define ND 512
#define QB 64
#define KB 256
#define MASK_VALUE (-1e-06f)
#define PLANE  ((size_t)NB * NK * ND)   // 8,388,608 elems per K/V plane
#define WPLANE ((size_t)ND * ND)

typedef __attribute__((ext_vector_type(4))) float f32x4;
typedef __attribute__((ext_vector_type(8))) __bf16 bf16x8;
typedef __attribute__((ext_vector_type(8))) _Float16 f16x8;
typedef __attribute__((ext_vector_type(4))) _Float16 f16x4;
typedef __attribute__((ext_vector_type(8))) unsigned short u16x8;
typedef __attribute__((ext_vector_type(4))) unsigned int u32x4;

typedef f32x4  __attribute__((may_alias)) f32x4_ma;
typedef bf16x8 __attribute__((may_alias)) bf16x8_ma;
typedef f16x8  __attribute__((may_alias)) f16x8_ma;
typedef f16x4  __attribute__((may_alias)) f16x4_ma;
typedef u32x4  __attribute__((may_alias)) u32x4_ma;

__device__ __forceinline__ unsigned short f2bf(float x){
    union { float f; unsigned u; } v; v.f = x;
    unsigned r = v.u + 0x7fffu + ((v.u >> 16) & 1u);
    return (unsigned short)(r >> 16);
}
__device__ __forceinline__ float bf2f(unsigned short h){
    union { unsigned u; float f; } v; v.u = ((unsigned)h) << 16;
    return v.f;
}

// ---------------- prep 1: K -> hi/lo fp16 planes, layout [b][k][e] ----------------
__global__ __launch_bounds__(256)
void split_k_f16_kernel(const float* __restrict__ K,
                        _Float16* __restrict__ kh,
                        _Float16* __restrict__ kl)
{
    const size_t i = ((size_t)blockIdx.x * 256 + threadIdx.x) * 4;
    const f32x4 v = *(const f32x4_ma*)(K + i);
    f16x4 h, l;
    #pragma unroll
    for (int c = 0; c < 4; ++c){
        h[c] = (_Float16)v[c];
        l[c] = (_Float16)(v[c] - (float)h[c]);
    }
    *(f16x4_ma*)(kh + i) = h;
    *(f16x4_ma*)(kl + i) = l;
}

// -------- prep 2: V -> single fp16 plane TRANSPOSED, layout [b][d][k] --------
__global__ __launch_bounds__(256)
void transpose_v_f16_kernel(const float* __restrict__ V,
                            _Float16* __restrict__ vt)
{
    __shared__ float t[64][68];
    const int tid = threadIdx.x;
    const int bid = blockIdx.x;
    const int dt  = bid & 7;
    const int kt  = (bid >> 3) & 31;
    const int b   = bid >> 8;
    {
        const int rr = tid >> 4;
        const int c4 = (tid & 15) * 4;
        #pragma unroll
        for (int m4 = 0; m4 < 4; ++m4){
            const int kr = rr + m4*16;
            *(f32x4_ma*)&t[kr][c4] =
                *(const f32x4_ma*)&V[((size_t)b*NK + kt*64 + kr)*ND + dt*64 + c4];
        }
    }
    __syncthreads();
    {
        const int dr = tid >> 2;
        const int kc = (tid & 3) * 16;
        f16x8 v0, v1;
        #pragma unroll
        for (int j = 0; j < 8; ++j) v0[j] = (_Float16)t[kc + j][dr];
        #pragma unroll
        for (int j = 0; j < 8; ++j) v1[j] = (_Float16)t[kc + 8 + j][dr];
        const size_t dst = ((size_t)b*ND + dt*64 + dr)*NK + kt*64 + kc;
        *(f16x8_ma*)(vt + dst)     = v0;
        *(f16x8_ma*)(vt + dst + 8) = v1;
    }
}

// -------- prep 3: W -> hi/lo bf16 planes TRANSPOSED, layout [e][d] --------
__global__ __launch_bounds__(256)
void transpose_split_w_kernel(const float* __restrict__ W,
                              unsigned short* __restrict__ wth,
                              unsigned short* __restrict__ wtl)
{
    __shared__ float t[64][68];
    const int tid = threadIdx.x;
    const int et  = blockIdx.x & 7;
    const int dt  = blockIdx.x >> 3;
    {
        const int rr = tid >> 4;
        const int c4 = (tid & 15) * 4;
        #pragma unroll
        for (int m4 = 0; m4 < 4; ++m4){
            const int dr = rr + m4*16;
            *(f32x4_ma*)&t[dr][c4] =
                *(const f32x4_ma*)&W[(size_t)(dt*64 + dr)*ND + et*64 + c4];
        }
    }
    __syncthreads();
    {
        const int er = tid >> 2;
        const int dc = (tid & 3) * 16;
        unsigned short hh[16], ll[16];
        #pragma unroll
        for (int j = 0; j < 16; ++j){
            const float v = t[dc + j][er];
            const unsigned short h = f2bf(v);
            hh[j] = h;
            ll[j] = f2bf(v - bf2f(h));
        }
        u32x4 h0, h1, l0, l1;
        #pragma unroll
        for (int c = 0; c < 4; ++c){
            h0[c] = (unsigned)hh[2*c]   | ((unsigned)hh[2*c+1] << 16);
            h1[c] = (unsigned)hh[8+2*c] | ((unsigned)hh[9+2*c] << 16);
            l0[c] = (unsigned)ll[2*c]   | ((unsigned)ll[2*c+1] << 16);
            l1[c] = (unsigned)ll[8+2*c] | ((unsigned)ll[9+2*c] << 16);
        }
        const size_t dst = (size_t)(et*64 + er)*ND + dt*64 + dc;
        *(u32x4_ma*)(wth + dst)     = h0;
        *(u32x4_ma*)(wth + dst + 8) = h1;
        *(u32x4_ma*)(wtl + dst)     = l0;
        *(u32x4_ma*)(wtl + dst + 8) = l1;
    }
}

// ---------------- main fused kernel: 16 waves, QB=64, KB=256, fp16 QK/PV ----------------
__global__ __launch_bounds__(1024, 4)
void attn_kernel(const float* __restrict__ Qp, const int* __restrict__ Mp,
                 const _Float16* __restrict__ Kh, const _Float16* __restrict__ Kl,
                 const _Float16* __restrict__ Vt,
                 const unsigned short* __restrict__ Wth, const unsigned short* __restrict__ Wtl,
                 float* __restrict__ Op)
{
    __shared__ _Float16 qw[QB][520];    // stride 520 = 8*65 -> optimal b128 banking
    __shared__ _Float16 p_b[QB][264];   // stride 264 = 8*33
    __shared__ float wredA[QB][16];     // ~104 KB total -> 1 block/CU (16 waves)

    const int tid  = threadIdx.x;
    const int lane = tid & 63;
    const int wv   = tid >> 6;              // wave 0..15
    const int lm   = lane & 15;
    const int lg   = lane >> 4;
    const int b    = blockIdx.x & 7;        // batch -> XCD affinity
    const int q0   = (int)(blockIdx.x >> 3) * QB;

    int mk;
    {   // tolerate int64-encoded masks (values >=1, so odd words all-zero => int64)
        const int odd = Mp[1] | Mp[3] | Mp[5] | Mp[7];
        mk = (odd == 0) ? Mp[2*b] : Mp[b];
    }

    // ===== Phase 1: qw[64][512] = Q_tile @ W via bf16 hi/lo 3-term MFMA =====
    // wave wv owns output cols [wv*32, +32)
    {
        f32x4 acc[4][2];
        #pragma unroll
        for (int m2 = 0; m2 < 4; ++m2)
            #pragma unroll
            for (int n2 = 0; n2 < 2; ++n2) acc[m2][n2] = (f32x4){0.f,0.f,0.f,0.f};

        for (int w = 0; w < 16; ++w){
            bf16x8 aH[4], aL[4];
            #pragma unroll
            for (int m2 = 0; m2 < 4; ++m2){
                const float* qp = Qp + ((size_t)b*NQ + q0 + m2*16 + lm)*ND + w*32 + lg*8;
                const f32x4 qa = *(const f32x4_ma*)qp;
                const f32x4 qb = *(const f32x4_ma*)(qp + 4);
                u16x8 hh, ll;
                #pragma unroll
                for (int c = 0; c < 4; ++c){
                    const unsigned short h = f2bf(qa[c]);
                    hh[c] = h; ll[c] = f2bf(qa[c] - bf2f(h));
                }
                #pragma unroll
                for (int c = 0; c < 4; ++c){
                    const unsigned short h = f2bf(qb[c]);
                    hh[4+c] = h; ll[4+c] = f2bf(qb[c] - bf2f(h));
                }
                aH[m2] = __builtin_bit_cast(bf16x8, hh);
                aL[m2] = __builtin_bit_cast(bf16x8, ll);
            }
            #pragma unroll
            for (int n2 = 0; n2 < 2; ++n2){
                const size_t wrow = (size_t)(wv*32 + n2*16 + lm)*ND + w*32 + lg*8;
                const bf16x8 bh = *(const bf16x8_ma*)(Wth + wrow);
                const bf16x8 bl = *(const bf16x8_ma*)(Wtl + wrow);
                #pragma unroll
                for (int m2 = 0; m2 < 4; ++m2){
                    acc[m2][n2] = __builtin_amdgcn_mfma_f32_16x16x32_bf16(aH[m2], bh, acc[m2][n2], 0,0,0);
                    acc[m2][n2] = __builtin_amdgcn_mfma_f32_16x16x32_bf16(aH[m2], bl, acc[m2][n2], 0,0,0);
                    acc[m2][n2] = __builtin_amdgcn_mfma_f32_16x16x32_bf16(aL[m2], bh, acc[m2][n2], 0,0,0);
                }
            }
        }
        // C-scatter (row = lg*4+r, col = lm; m89-verified) -> fp16 qw in LDS
        #pragma unroll
        for (int m2 = 0; m2 < 4; ++m2)
            #pragma unroll
            for (int n2 = 0; n2 < 2; ++n2)
                #pragma unroll
                for (int r = 0; r < 4; ++r)
                    qw[m2*16 + lg*4 + r][wv*32 + n2*16 + lm] = (_Float16)acc[m2][n2][r];
    }
    __syncthreads();

    // ===== Phase 2: flash loop over 8 tiles of 256 keys =====
    float m_run[4][4];
    #pragma unroll
    for (int m2 = 0; m2 < 4; ++m2)
        #pragma unroll
        for (int r = 0; r < 4; ++r) m_run[m2][r] = -3.0e38f;

    f32x4 o_acc[4][2];   // wave's d-slice: [wv*32, +32)
    f32x4 l_acc[4];      // denominator via ones-MFMA (consistent with PV numerator)
    #pragma unroll
    for (int m2 = 0; m2 < 4; ++m2){
        l_acc[m2] = (f32x4){0.f,0.f,0.f,0.f};
        #pragma unroll
        for (int n = 0; n < 2; ++n) o_acc[m2][n] = (f32x4){0.f,0.f,0.f,0.f};
    }

    f16x8 ones;
    #pragma unroll
    for (int j = 0; j < 8; ++j) ones[j] = (_Float16)1.0f;

    const _Float16* khb = Kh + ((size_t)b*NK + wv*16 + lm)*ND;
    const _Float16* klb = Kl + ((size_t)b*NK + wv*16 + lm)*ND;
    const size_t vbase = ((size_t)b*ND + wv*32 + lm)*NK + lg*8;

    for (int k0 = 0; k0 < NK; k0 += KB){
        const size_t koff = (size_t)k0 * ND;

        // ---- QK^T (fp16 2-term): wave wv owns key-cols [wv*16,+16) of the 256-tile ----
        f32x4 sacc[4];
        #pragma unroll
        for (int m2 = 0; m2 < 4; ++m2) sacc[m2] = (f32x4){0.f,0.f,0.f,0.f};
        #pragma unroll
        for (int w = 0; w < 16; ++w){
            const int eoff = w*32 + lg*8;
            const f16x8 bh = *(const f16x8_ma*)(khb + koff + eoff);
            const f16x8 bl = *(const f16x8_ma*)(klb + koff + eoff);
            #pragma unroll
            for (int m2 = 0; m2 < 4; ++m2){
                const f16x8 aQ = *(const f16x8_ma*)&qw[m2*16 + lm][eoff];
                sacc[m2] = __builtin_amdgcn_mfma_f32_16x16x32_f16(aQ, bh, sacc[m2], 0,0,0);
                sacc[m2] = __builtin_amdgcn_mfma_f32_16x16x32_f16(aQ, bl, sacc[m2], 0,0,0);
            }
        }

        // ---- faithful mask (lane-local key: k0 + wv*16 + lm) ----
        const bool inval = (k0 + wv*16 + lm) >= mk;
        float sv[4][4];
        #pragma unroll
        for (int m2 = 0; m2 < 4; ++m2)
            #pragma unroll
            for (int r = 0; r < 4; ++r) sv[m2][r] = inval ? MASK_VALUE : sacc[m2][r];

        // ---- per-wave row max over its 16 keys (4 shuffles), publish ----
        float pm[4][4];
        #pragma unroll
        for (int m2 = 0; m2 < 4; ++m2)
            #pragma unroll
            for (int r = 0; r < 4; ++r) pm[m2][r] = sv[m2][r];
        #pragma unroll
        for (int off = 1; off < 16; off <<= 1)
            #pragma unroll
            for (int m2 = 0; m2 < 4; ++m2)
                #pragma unroll
                for (int r = 0; r < 4; ++r)
                    pm[m2][r] = fmaxf(pm[m2][r], __shfl_xor(pm[m2][r], off, 64));
        if (lm == 0){
            #pragma unroll
            for (int m2 = 0; m2 < 4; ++m2)
                #pragma unroll
                for (int r = 0; r < 4; ++r) wredA[m2*16 + lg*4 + r][wv] = pm[m2][r];
        }
        __syncthreads();

        // ---- mnew, fsc, p = exp(s - mnew) -> fp16 to LDS ----
        float fsc[4][4];
        #pragma unroll
        for (int m2 = 0; m2 < 4; ++m2)
            #pragma unroll
            for (int r = 0; r < 4; ++r){
                const int row = m2*16 + lg*4 + r;
                const f32x4 g0 = *(const f32x4_ma*)&wredA[row][0];
                const f32x4 g1 = *(const f32x4_ma*)&wredA[row][4];
                const f32x4 g2 = *(const f32x4_ma*)&wredA[row][8];
                const f32x4 g3 = *(const f32x4_ma*)&wredA[row][12];
                float gm = fmaxf(fmaxf(fmaxf(g0[0],g0[1]),fmaxf(g0[2],g0[3])),
                                 fmaxf(fmaxf(g1[0],g1[1]),fmaxf(g1[2],g1[3])));
                gm = fmaxf(gm, fmaxf(fmaxf(fmaxf(g2[0],g2[1]),fmaxf(g2[2],g2[3])),
                                     fmaxf(fmaxf(g3[0],g3[1]),fmaxf(g3[2],g3[3]))));
                const float mnew = fmaxf(m_run[m2][r], gm);
                fsc[m2][r] = __expf(m_run[m2][r] - mnew);
                m_run[m2][r] = mnew;
                p_b[row][wv*16 + lm] = (_Float16)__expf(sv[m2][r] - mnew);
            }
        __syncthreads();

        // ---- rescale, then PV + ones-MFMA denominator ----
        #pragma unroll
        for (int m2 = 0; m2 < 4; ++m2){
            #pragma unroll
            for (int r = 0; r < 4; ++r){
                o_acc[m2][0][r] *= fsc[m2][r];
                o_acc[m2][1][r] *= fsc[m2][r];
                l_acc[m2][r]    *= fsc[m2][r];
            }
        }
        #pragma unroll
        for (int kb = 0; kb < 8; ++kb){
            f16x8 pa[4];
            #pragma unroll
            for (int m2 = 0; m2 < 4; ++m2)
                pa[m2] = *(const f16x8_ma*)&p_b[m2*16 + lm][kb*32 + lg*8];
            #pragma unroll
            for (int n = 0; n < 2; ++n){
                const f16x8 vv = *(const f16x8_ma*)(Vt + vbase + (size_t)n*16*NK + k0 + kb*32);
                #pragma unroll
                for (int m2 = 0; m2 < 4; ++m2)
                    o_acc[m2][n] = __builtin_amdgcn_mfma_f32_16x16x32_f16(pa[m2], vv, o_acc[m2][n], 0,0,0);
            }
            #pragma unroll
            for (int m2 = 0; m2 < 4; ++m2)
                l_acc[m2] = __builtin_amdgcn_mfma_f32_16x16x32_f16(pa[m2], ones, l_acc[m2], 0,0,0);
        }
    }

    // ===== epilogue: normalize with the consistent denominator =====
    #pragma unroll
    for (int m2 = 0; m2 < 4; ++m2){
        float li[4];
        #pragma unroll
        for (int r = 0; r < 4; ++r) li[r] = 1.f / l_acc[m2][r];
        #pragma unroll
        for (int n = 0; n < 2; ++n)
            #pragma unroll
            for (int r = 0; r < 4; ++r)
                Op[((size_t)b*NQ + q0 + m2*16 + lg*4 + r)*ND + wv*32 + n*16 + lm]
                    = o_acc[m2][n][r] * li[r];
    }
}

extern "C" void kernel_launch(void* const* d_in, const int* in_sizes, int n_in,
                              void* d_out, int out_size, void* d_ws, size_t ws_size,
                              hipStream_t stream)
{
    (void)in_sizes; (void)n_in; (void)out_size; (void)ws_size;
    const float* Qp = (const float*)d_in[0];
    const float* Kp = (const float*)d_in[1];
    const float* Vp = (const float*)d_in[2];
    const float* Wp = (const float*)d_in[3];
    const int*   Mp = (const int*)  d_in[4];
    float* Op = (float*)d_out;

    unsigned short* wsu = (unsigned short*)d_ws;   // 51.4 MB total (proven size)
    _Float16*       Kh  = (_Float16*)wsu;
    _Float16*       Kl  = (_Float16*)(wsu + PLANE);
    _Float16*       Vt  = (_Float16*)(wsu + 2*PLANE);
    unsigned short* Wth = wsu + 3*PLANE;
    unsigned short* Wtl = wsu + 3*PLANE + WPLANE;

    hipLaunchKernelGGL(split_k_f16_kernel, dim3(PLANE/1024), dim3(256), 0, stream,
                       Kp, Kh, Kl);
    hipLaunchKernelGGL(transpose_v_f16_kernel, dim3(NB*32*8), dim3(256), 0, stream,
                       Vp, Vt);
    hipLaunchKernelGGL(transpose_split_w_kernel, dim3(64), dim3(256), 0, stream,
                       Wp, Wth, Wtl);
    hipLaunchKernelGGL(attn_kernel, dim3(NB*(NQ/QB)), dim3(1024), 0, stream,
                       Qp, Mp, Kh, Kl, Vt, Wth, Wtl, Op);
}